// Round 19
// baseline (198.016 us; speedup 1.0000x reference)
//
#include <hip/hip_runtime.h>
#include <hip/hip_bf16.h>

typedef __attribute__((ext_vector_type(8))) short short8;
typedef __attribute__((ext_vector_type(4))) short short4v;
typedef __attribute__((ext_vector_type(4))) float f32x4;

#define LDSTB 520            // B LDS row: 512 + 8 pad bf16 -> 8-touch/bank frag reads (min)
#define LDSTA 74             // A LDS row: 64 + 10 pad bf16 -> odd dword stride 37 (spread)
#define B_ELE (64 * LDSTB)   // 33280 u16
#define A_BUF (32 * LDSTA)   // 2368 u16 per buffer
#define LDS_BYTES ((B_ELE + 16 * A_BUF) * 2)   // 142336 B

static __device__ __forceinline__ unsigned short f2bf(float f) {
    union { __hip_bfloat16 h; unsigned short u; } cv;
    cv.h = __float2bfloat16(f);
    return cv.u;
}

// Build WbigS: octonion-folded weight, bf16, plain [m][512] rows with the
// k-granule XOR baked in: logical granule g=(kk>>3)&3 of col m stored at
// slot g^(m&3) within each 32-K group.
//   idx = m*512 + (kk>>5)*32 + ((((kk>>3)&3) ^ (m&3))*8) + (kk&7)
__global__ __launch_bounds__(256) void build_wbig(const float* __restrict__ W,
                                                  unsigned short* __restrict__ WbigS) {
    __shared__ float C[8][8][8];
    const int t = threadIdx.x;
    for (int i = t; i < 512; i += 256) ((float*)C)[i] = 0.0f;
    __syncthreads();
    if (t == 0) {
        C[0][0][0] = 1.0f;
        for (int i = 1; i < 8; ++i) { C[0][i][i] = 1.0f; C[i][0][i] = 1.0f; C[i][i][0] = -1.0f; }
        const int tr[7][3] = {{1,2,3},{1,4,5},{1,7,6},{2,4,6},{2,5,7},{3,4,7},{3,6,5}};
        for (int q = 0; q < 7; ++q) {
            const int a = tr[q][0], b = tr[q][1], c = tr[q][2];
            const int p[3][3] = {{a,b,c},{b,c,a},{c,a,b}};
            for (int u = 0; u < 3; ++u) {
                C[p[u][0]][p[u][1]][p[u][2]] = 1.0f;
                C[p[u][1]][p[u][0]][p[u][2]] = -1.0f;
            }
        }
    }
    __syncthreads();
    const int e = blockIdx.x * 256 + t;     // 0..262143
    const int m = e >> 9, kk = e & 511;
    const int o = m >> 3, k = m & 7, f = kk >> 3, j = kk & 7;
    float s = 0.0f;
#pragma unroll
    for (int i = 0; i < 8; ++i) s += C[i][j][k] * W[i * 4096 + o * 64 + f];

    const int idx = m * 512 + ((kk >> 5) * 32) + (((((kk >> 3) & 3) ^ (m & 3))) * 8) + (kk & 7);
    WbigS[idx] = f2bf(s);
}

// Out[65536][512] = X(fp32->bf16) * Wbig^T + bias.
// BARRIER-FREE pipeline via wave-private A staging:
//  - Block (512 thr, 8 waves) owns 256 rows x 64 cols. B panel (64x512 bf16,
//    XOR pre-baked, stride-520 pad) staged once -> ONE __syncthreads -> done.
//  - Each wave owns rows [w*32, w*32+32): stages its strip into a PRIVATE
//    LDS double-buffer (stride-74 pad). All ordering is wave-local
//    (compiler-counted vmcnt/lgkmcnt). ZERO barriers in the K loop.
//  - Depth-2 register ring (2 sets x 32 VGPR); chunk t+2 in flight while
//    computing chunk t; ds_write of t+1 waits only its own 8 loads.
//  - XCD swizzle: the 8 col-group blocks of a 256-row stripe share an XCD
//    (X slice 512 KB <= 4 MB L2) -> X HBM-fetched once.
__global__ __launch_bounds__(512, 2) void oct_gemm(const float* __restrict__ X,
                                                   const unsigned short* __restrict__ WbigS,
                                                   const float* __restrict__ Bias,
                                                   float* __restrict__ Out) {
    extern __shared__ unsigned short smem[];
    unsigned short* Bs = smem;                    // [64][520]
    unsigned short* Aw = smem + B_ELE;            // 16 x [32][74]

    const int bid = blockIdx.x;          // 0..2047
    const int xcd = bid & 7;
    const int j   = bid >> 3;            // 0..255
    const int rowBlk = xcd * 32 + (j >> 3);   // 0..255
    const int cg     = j & 7;                 // 0..7
    const int rowBase = rowBlk * 256;
    const int colBase = cg * 64;

    const int t    = threadIdx.x;        // 0..511
    const int lane = t & 63;
    const int w    = t >> 6;             // 0..7
    const int l15  = lane & 15;
    const int l4   = lane >> 4;          // 0..3

    unsigned short* Abuf[2] = { Aw + (w * 2 + 0) * A_BUF, Aw + (w * 2 + 1) * A_BUF };

    // ---- stage B panel once (64 rows x 512 bf16 from L2-hot WbigS) ----
    {
        const int r = t >> 3, c0 = (t & 7) * 64;
#pragma unroll
        for (int q = 0; q < 8; ++q) {
            short8 v = *reinterpret_cast<const short8*>(
                WbigS + (size_t)(colBase + r) * 512 + c0 + q * 8);
            *reinterpret_cast<short8*>(&Bs[r * LDSTB + c0 + q * 8]) = v;
        }
    }
    __syncthreads();   // the ONLY barrier in the kernel

    // Wave-private A strip base: rows rowBase + w*32 ..+31.
    const float* Xw = X + (size_t)(rowBase + w * 32) * 512;

    f32x4 set0[8], set1[8];   // depth-2 ring (64 VGPR)

    // slot s = i*64+lane: row s>>4 (0..31), col (s&15)*4 within the 64-K chunk
#define AISSUE(SET, CH) do { _Pragma("unroll") \
    for (int i = 0; i < 8; ++i) { \
        const int s = i * 64 + lane; \
        SET[i] = *reinterpret_cast<const f32x4*>( \
            Xw + (size_t)(s >> 4) * 512 + (CH) * 64 + (s & 15) * 4); \
    } } while (0)

#define AWRITE(SET, BUF) do { _Pragma("unroll") \
    for (int i = 0; i < 8; ++i) { \
        const int s = i * 64 + lane; \
        short4v pk; \
        pk[0] = (short)f2bf(SET[i][0]); pk[1] = (short)f2bf(SET[i][1]); \
        pk[2] = (short)f2bf(SET[i][2]); pk[3] = (short)f2bf(SET[i][3]); \
        *reinterpret_cast<short4v*>(&Abuf[BUF][(s >> 4) * LDSTA + (s & 15) * 4]) = pk; \
    } } while (0)

    // Bias folded into accumulator init (D col = lane&15 for all 4 regs).
    f32x4 acc[2][4];
#pragma unroll
    for (int ni = 0; ni < 4; ++ni) {
        const float bv = Bias[colBase + ni * 16 + l15];
        acc[0][ni] = (f32x4){bv, bv, bv, bv};
        acc[1][ni] = (f32x4){bv, bv, bv, bv};
    }

    // Prologue (wave-local): chunks 0,1 in flight; write chunk 0.
    AISSUE(set0, 0);
    AISSUE(set1, 1);
    AWRITE(set0, 0);   // compiler-counted vmcnt: waits only set0's 8 loads

    // ---- barrier-free K loop: 8 tiles of K=64 ----
#pragma unroll
    for (int kt = 0; kt < 8; ++kt) {
        // issue chunk kt+2 into the set that held chunk kt (freed last iter)
        if (kt + 2 < 8) { if ((kt & 1) == 0) AISSUE(set0, kt + 2); else AISSUE(set1, kt + 2); }

        // compute on Abuf[kt&1] + B panel (all LDS, wave-local lgkmcnt)
#pragma unroll
        for (int kk = 0; kk < 2; ++kk) {
            short8 bfr[4];
#pragma unroll
            for (int ni = 0; ni < 4; ++ni) {
                const int c = ni * 16 + l15;   // c&3 == l15&3
                bfr[ni] = *reinterpret_cast<const short8*>(
                    &Bs[c * LDSTB + (kt * 2 + kk) * 32 + ((l4 ^ (l15 & 3)) << 3)]);
            }
#pragma unroll
            for (int mi = 0; mi < 2; ++mi) {
                const short8 a = *reinterpret_cast<const short8*>(
                    &Abuf[kt & 1][(mi * 16 + l15) * LDSTA + kk * 32 + l4 * 8]);
#pragma unroll
                for (int ni = 0; ni < 4; ++ni)
                    acc[mi][ni] = __builtin_amdgcn_mfma_f32_16x16x32_bf16(
                        a, bfr[ni], acc[mi][ni], 0, 0, 0);
            }
        }

        // write chunk kt+1 into the other buffer (waits only its own loads)
        if (kt + 1 < 8) { if ((kt & 1) == 0) AWRITE(set1, 1); else AWRITE(set0, 0); }
    }

    // Epilogue: plain fp32 stores (verified clean 131 MB pattern).
#pragma unroll
    for (int mi = 0; mi < 2; ++mi) {
        const int row0 = rowBase + w * 32 + mi * 16 + l4 * 4;
#pragma unroll
        for (int ni = 0; ni < 4; ++ni) {
            const int col = colBase + ni * 16 + l15;
#pragma unroll
            for (int r = 0; r < 4; ++r)
                Out[(size_t)(row0 + r) * 512 + col] = acc[mi][ni][r];
        }
    }
#undef AISSUE
#undef AWRITE
}

extern "C" void kernel_launch(void* const* d_in, const int* in_sizes, int n_in,
                              void* d_out, int out_size, void* d_ws, size_t ws_size,
                              hipStream_t stream) {
    const float* x = (const float*)d_in[0];   // [65536][512]
    const float* W = (const float*)d_in[1];   // [8][64][64]
    const float* b = (const float*)d_in[2];   // [512]
    float* out = (float*)d_out;               // [65536][512]
    unsigned short* WbigS = (unsigned short*)d_ws;  // 512 KB, granule-XOR baked

    static bool attr_done = false;
    if (!attr_done) {
        hipFuncSetAttribute((const void*)oct_gemm,
                            hipFuncAttributeMaxDynamicSharedMemorySize, LDS_BYTES);
        attr_done = true;
    }

    build_wbig<<<1024, 256, 0, stream>>>(W, WbigS);
    oct_gemm<<<2048, 512, LDS_BYTES, stream>>>(x, WbigS, b, out);
}

// Round 20
// 78.743 us; speedup vs baseline: 2.5147x; 2.5147x over previous
//
#include <hip/hip_runtime.h>
#include <hip/hip_bf16.h>

typedef __attribute__((ext_vector_type(8))) short short8;
typedef __attribute__((ext_vector_type(4))) float f32x4;
typedef __attribute__((address_space(1))) const unsigned int as1_u32;
typedef __attribute__((address_space(3))) unsigned int as3_u32;

#define BM 128
#define BN 128
#define BK 64
#define NKT 8
#define LDSTA 72                // A row: 64 + 8 pad bf16 (verified R1-R17)
#define A_ELE (128 * LDSTA)     // 9216 per buf

static __device__ __forceinline__ unsigned short f2bf(float f) {
    union { __hip_bfloat16 h; unsigned short u; } cv;
    cv.h = __float2bfloat16(f);
    return cv.u;
}

__device__ __forceinline__ void gload16(const void* g, void* l) {
    __builtin_amdgcn_global_load_lds((as1_u32*)g, (as3_u32*)l, 16, 0, 0);
}

// Build WbigS (VERIFIED R16/R17): octonion-folded weight, bf16, pre-swizzled.
// Logical Wbig[m][kk] = sum_i C[i,j,k]*W[i,o,f]  (m=o*8+k col, kk=f*8+j K).
// Chunk (nt=m>>7, H=kk>>5) = 128 cols x 32 K, gloaded linearly; within chunk
// col c=m&127, logical granule q=(kk>>3)&3 stored at q^(c&3), elem e=kk&7:
//   idx = (nt*16+H)*4096 + c*32 + (q^(c&3))*8 + e
__global__ __launch_bounds__(256) void build_wbig(const float* __restrict__ W,
                                                  unsigned short* __restrict__ WbigS) {
    __shared__ float C[8][8][8];
    const int t = threadIdx.x;
    for (int i = t; i < 512; i += 256) ((float*)C)[i] = 0.0f;
    __syncthreads();
    if (t == 0) {
        C[0][0][0] = 1.0f;
        for (int i = 1; i < 8; ++i) { C[0][i][i] = 1.0f; C[i][0][i] = 1.0f; C[i][i][0] = -1.0f; }
        const int tr[7][3] = {{1,2,3},{1,4,5},{1,7,6},{2,4,6},{2,5,7},{3,4,7},{3,6,5}};
        for (int q = 0; q < 7; ++q) {
            const int a = tr[q][0], b = tr[q][1], c = tr[q][2];
            const int p[3][3] = {{a,b,c},{b,c,a},{c,a,b}};
            for (int u = 0; u < 3; ++u) {
                C[p[u][0]][p[u][1]][p[u][2]] = 1.0f;
                C[p[u][1]][p[u][0]][p[u][2]] = -1.0f;
            }
        }
    }
    __syncthreads();
    const int e = blockIdx.x * 256 + t;     // 0..262143
    const int m = e >> 9, kk = e & 511;
    const int o = m >> 3, k = m & 7, f = kk >> 3, j = kk & 7;
    float s = 0.0f;
#pragma unroll
    for (int i = 0; i < 8; ++i) s += C[i][j][k] * W[i * 4096 + o * 64 + f];

    const int nt = m >> 7, c = m & 127;
    const int H = kk >> 5, q = (kk >> 3) & 3, e8 = kk & 7;
    WbigS[((nt * 16 + H) * 4096) + c * 32 + ((q ^ (c & 3)) * 8) + e8] = f2bf(s);
}

// Out[65536][512] = X(fp32->bf16) * Wbig^T + bias.
// THE UNTESTED COMBINATION: R17's co-resident geometry (128x128, 8 waves,
// LDS 68 KB => 2 blocks/CU, 16 waves/CU) + R12's no-drain schedule (depth-2
// A ring, B via global_load_lds, counted vmcnt barriers, sched_barrier pins).
// Queue per iter kt (oldest->newest at barrier): A(t+1)[4 retired by WRITE's
// counted vmcnt(6)], B(t+1)[2 retired by end vmcnt(4)], A(t+2)[4 left flying].
__global__ __launch_bounds__(512, 4) void oct_gemm(const float* __restrict__ X,
                                                   const unsigned short* __restrict__ WbigS,
                                                   const float* __restrict__ Bias,
                                                   float* __restrict__ Out) {
    __shared__ unsigned short As[2][A_ELE];    // 2 x 18 KB, stride-72 pad
    __shared__ unsigned short Bs[2][2][4096];  // 2 buf x 2 kk-halves x 8 KB

    // XCD swizzle: the 4 col-tiles of each row-tile on one XCD (share A in L2).
    const int bid = blockIdx.x;          // 0..2047
    const int xcd = bid & 7;
    const int ix  = bid >> 3;            // 0..255
    const int mtile = xcd * 64 + (ix >> 2);
    const int nt    = ix & 3;
    const int rowBase = mtile * BM;
    const int colBase = nt * BN;

    const int t    = threadIdx.x;        // 0..511
    const int lane = t & 63;
    const int w    = t >> 6;             // 0..7
    const int wr   = w >> 2;             // 0..1 (64-row half)
    const int wc   = w & 3;              // 0..3 (32-col quarter)
    const int l15  = lane & 15;
    const int l4   = lane >> 4;          // 0..3

    // A staging: 4 thr/row, 16 consecutive fp32 (64 B) each (R17-verified).
    const int srow = t >> 2;             // 0..127
    const int scol = (t & 3) * 16;       // 0, 16, 32, 48
    const float* Xp = X + (size_t)(rowBase + srow) * 512 + scol;

    // B gload source (R16/R17-verified stream).
    const unsigned short* Bsrc = WbigS + nt * (16 * 4096) + t * 8;

    f32x4 va0[4], va1[4];                // depth-2 ring (32 VGPR)

#define ISSUE_A(VA, KT) do { _Pragma("unroll") \
    for (int l = 0; l < 4; ++l) \
        VA[l] = *reinterpret_cast<const f32x4*>(Xp + (KT) * BK + l * 4); \
    } while (0)

#define GLOAD_B(BUF, KT) do { _Pragma("unroll") \
    for (int kk = 0; kk < 2; ++kk) \
        gload16(Bsrc + (2 * (KT) + kk) * 4096, &Bs[BUF][kk][w * 512]); \
    } while (0)

#define WRITE_A(VA, BUF) do { \
    short8 p0, p1; \
    p0[0]=(short)f2bf(VA[0][0]); p0[1]=(short)f2bf(VA[0][1]); \
    p0[2]=(short)f2bf(VA[0][2]); p0[3]=(short)f2bf(VA[0][3]); \
    p0[4]=(short)f2bf(VA[1][0]); p0[5]=(short)f2bf(VA[1][1]); \
    p0[6]=(short)f2bf(VA[1][2]); p0[7]=(short)f2bf(VA[1][3]); \
    p1[0]=(short)f2bf(VA[2][0]); p1[1]=(short)f2bf(VA[2][1]); \
    p1[2]=(short)f2bf(VA[2][2]); p1[3]=(short)f2bf(VA[2][3]); \
    p1[4]=(short)f2bf(VA[3][0]); p1[5]=(short)f2bf(VA[3][1]); \
    p1[6]=(short)f2bf(VA[3][2]); p1[7]=(short)f2bf(VA[3][3]); \
    *reinterpret_cast<short8*>(&As[BUF][srow * LDSTA + scol]) = p0; \
    *reinterpret_cast<short8*>(&As[BUF][srow * LDSTA + scol + 8]) = p1; \
    } while (0)

    // Bias folded into accumulator init (D col = lane&15 for all 4 regs).
    f32x4 acc[4][2];
#pragma unroll
    for (int ni = 0; ni < 2; ++ni) {
        const float bv = Bias[colBase + wc * 32 + ni * 16 + l15];
#pragma unroll
        for (int mi = 0; mi < 4; ++mi) acc[mi][ni] = (f32x4){bv, bv, bv, bv};
    }

    // Prologue. Queue (oldest->newest): A0[4], B0[2], A1[4].
    ISSUE_A(va0, 0);
    GLOAD_B(0, 0);
    ISSUE_A(va1, 1);
    WRITE_A(va0, 0);                                      // counted vmcnt(6): A0 done
    asm volatile("s_waitcnt vmcnt(4) lgkmcnt(0)" ::: "memory");   // B0 done; A1 flying
    __builtin_amdgcn_s_barrier();

#pragma unroll
    for (int kt = 0; kt < NKT; ++kt) {
        const int buf = kt & 1, nbuf = buf ^ 1;

        // Issue next tile: B first (oldest), then A(t+2) into the freed set.
        if (kt + 1 < NKT) GLOAD_B(nbuf, kt + 1);
        if (kt + 2 < NKT) { if ((kt & 1) == 0) ISSUE_A(va0, kt + 2); else ISSUE_A(va1, kt + 2); }
        __builtin_amdgcn_sched_barrier(0);

        // MFMA phase: LDS-only operands (R17-verified frag maps).
#pragma unroll
        for (int kk = 0; kk < 2; ++kk) {
            short8 b[2];
#pragma unroll
            for (int ni = 0; ni < 2; ++ni) {
                const int c = wc * 32 + ni * 16 + l15;
                b[ni] = *reinterpret_cast<const short8*>(
                    &Bs[buf][kk][c * 32 + ((l4 ^ (l15 & 3)) << 3)]);
            }
            __builtin_amdgcn_s_setprio(1);
#pragma unroll
            for (int mi = 0; mi < 4; ++mi) {
                const short8 a = *reinterpret_cast<const short8*>(
                    &As[buf][(wr * 64 + mi * 16 + l15) * LDSTA + kk * 32 + l4 * 8]);
#pragma unroll
                for (int ni = 0; ni < 2; ++ni)
                    acc[mi][ni] = __builtin_amdgcn_mfma_f32_16x16x32_bf16(
                        a, b[ni], acc[mi][ni], 0, 0, 0);
            }
            __builtin_amdgcn_s_setprio(0);
        }
        __builtin_amdgcn_sched_barrier(0);

        // Stage A(t+1): counted vmcnt(6) retires exactly A(t+1)'s 4 loads.
        if (kt + 1 < NKT) { if ((kt & 1) == 0) WRITE_A(va1, nbuf); else WRITE_A(va0, nbuf); }

        // End-of-iter: retire B(t+1), keep A(t+2) in flight. Never drain mid-loop.
        if (kt + 2 < NKT)
            asm volatile("s_waitcnt vmcnt(4) lgkmcnt(0)" ::: "memory");
        else if (kt + 1 < NKT)
            asm volatile("s_waitcnt vmcnt(0) lgkmcnt(0)" ::: "memory");
        if (kt + 1 < NKT) __builtin_amdgcn_s_barrier();
    }

    // Epilogue: plain fp32 stores (verified clean 131 MB pattern).
#pragma unroll
    for (int mi = 0; mi < 4; ++mi) {
        const int row0 = rowBase + wr * 64 + mi * 16 + l4 * 4;
#pragma unroll
        for (int ni = 0; ni < 2; ++ni) {
            const int col = colBase + wc * 32 + ni * 16 + l15;
#pragma unroll
            for (int r = 0; r < 4; ++r)
                Out[(size_t)(row0 + r) * 512 + col] = acc[mi][ni][r];
        }
    }
#undef ISSUE_A
#undef GLOAD_B
#undef WRITE_A
}

extern "C" void kernel_launch(void* const* d_in, const int* in_sizes, int n_in,
                              void* d_out, int out_size, void* d_ws, size_t ws_size,
                              hipStream_t stream) {
    const float* x = (const float*)d_in[0];   // [65536][512]
    const float* W = (const float*)d_in[1];   // [8][64][64]
    const float* b = (const float*)d_in[2];   // [512]
    float* out = (float*)d_out;               // [65536][512]
    unsigned short* WbigS = (unsigned short*)d_ws;  // 512 KB pre-swizzled stream

    build_wbig<<<1024, 256, 0, stream>>>(W, WbigS);
    oct_gemm<<<2048, 512, 0, stream>>>(x, WbigS, b, out);
}